// Round 1
// 530.322 us; speedup vs baseline: 2.2145x; 2.2145x over previous
//
#include <hip/hip_runtime.h>

#define DIM    256
#define HEADS  8
#define DH     64
#define DPG    32
#define KNB    32
#define INNER  512
#define EPS    1e-5f

// ws float offsets
#define WS_SUM  0
#define WS_SSQ  256
#define WS_SC   512
#define WS_SH   768
#define WS_WF   1024      // bf16 [3][8][64][32] folded weights  -> 24576 floats
#define WS_QB   25600     // f32  [3][8][64] folded biases       -> 1536 floats
#define WS_WT   27136     // bf16 [256][512] WoutT               -> 65536 floats (end 92672 floats = 371KB)

typedef float f32x4  __attribute__((ext_vector_type(4)));
typedef short bf16x8 __attribute__((ext_vector_type(8)));

__device__ __forceinline__ unsigned short f2bf(float f){
    unsigned u = __float_as_uint(f);
    u += 0x7fffu + ((u >> 16) & 1u);          // RNE
    return (unsigned short)(u >> 16);
}
__device__ __forceinline__ unsigned packbf(float a, float b){
    return (unsigned)f2bf(a) | ((unsigned)f2bf(b) << 16);
}
__device__ __forceinline__ bf16x8 pack8(f32x4 a, f32x4 b){
    union { unsigned u[4]; bf16x8 v; } r;
    r.u[0] = packbf(a[0], a[1]); r.u[1] = packbf(a[2], a[3]);
    r.u[2] = packbf(b[0], b[1]); r.u[3] = packbf(b[2], b[3]);
    return r.v;
}

// ---------------- BN statistics (vectorized float4) ----------------
__global__ __launch_bounds__(256) void bn_stats_k(const f32x4* __restrict__ x4,
                                                  float* __restrict__ ws, int n4) {
    __shared__ f32x4 rs[4][64], rss[4][64];
    int tid = blockIdx.x * 256 + threadIdx.x;
    int stride = gridDim.x * 256;
    f32x4 s  = {0.f, 0.f, 0.f, 0.f};
    f32x4 ss = {0.f, 0.f, 0.f, 0.f};
    for (int f = tid; f < n4; f += stride) {     // stride % 64 == 0 -> c4 invariant
        f32x4 v = x4[f];
        s += v; ss += v * v;
    }
    int c4 = threadIdx.x & 63, wv = threadIdx.x >> 6;
    rs[wv][c4] = s; rss[wv][c4] = ss;
    __syncthreads();
    if (threadIdx.x < 64) {
        int c = threadIdx.x;
        f32x4 S = rs[0][c] + rs[1][c] + rs[2][c] + rs[3][c];
        f32x4 Q = rss[0][c] + rss[1][c] + rss[2][c] + rss[3][c];
        #pragma unroll
        for (int j = 0; j < 4; ++j) {
            atomicAdd(&ws[WS_SUM + c * 4 + j], S[j]);
            atomicAdd(&ws[WS_SSQ + c * 4 + j], Q[j]);
        }
    }
}

__global__ __launch_bounds__(256) void bn_finalize_k(const float* __restrict__ g,
                                                     const float* __restrict__ b,
                                                     float* __restrict__ ws, float inv_n) {
    int c = threadIdx.x;
    float mean = ws[WS_SUM + c] * inv_n;
    float var  = ws[WS_SSQ + c] * inv_n - mean * mean;
    float sc   = g[c] * rsqrtf(var + EPS);
    ws[WS_SC + c] = sc;
    ws[WS_SH + c] = b[c] - mean * sc;
}

// ---------------- Wout transpose to bf16 ----------------
__global__ __launch_bounds__(256) void wt_k(const float* __restrict__ Wout, float* __restrict__ ws) {
    int k = blockIdx.x;          // 0..511
    int n = threadIdx.x;         // 0..255
    unsigned short* wt = (unsigned short*)(ws + WS_WT);
    wt[n * INNER + k] = f2bf(Wout[k * DIM + n]);
}

// ---------------- fold BN into QKV weights/biases (bf16 [o][c] per head) ----------------
__global__ __launch_bounds__(64) void fold_k(const float* __restrict__ Wq,
                                             const float* __restrict__ Wk,
                                             const float* __restrict__ Wv,
                                             float* __restrict__ ws) {
    int m = blockIdx.x, h = blockIdx.y, o = threadIdx.x;
    const float* W  = (m == 0 ? Wq : (m == 1 ? Wk : Wv)) + (h * DH + o) * DPG;
    const float* sc = ws + WS_SC + h * DPG;
    const float* sh = ws + WS_SH + h * DPG;
    float qsc = (m == 0) ? 0.125f : 1.f;          // dim_head^-0.5 folded into q
    unsigned short* wf = (unsigned short*)(ws + WS_WF) + ((m * HEADS + h) * DH + o) * DPG;
    float bias = 0.f;
    #pragma unroll
    for (int c = 0; c < DPG; ++c) {
        wf[c] = f2bf(W[c] * sc[c] * qsc);
        bias += sh[c] * W[c];
    }
    ws[WS_QB + (m * HEADS + h) * DH + o] = bias * qsc;
}

// ---------------- fused BN + QKV + attention + output GEMM (all MFMA) ----------------
// grid = npts (4096), block = 256 (4 waves). Wave w handles heads {w, w+4} of its point.
// MFMA 16x16x32 fragment convention (verified): A/B frag: lane&15 = row, lane>>4 = k-octet,
// 8 contiguous k per lane. D: col = lane&15, row = (lane>>4)*4 + reg.
__global__ __launch_bounds__(256, 2) void attn_fused(const float* __restrict__ x,
                                                     const float* __restrict__ ws,
                                                     const float* __restrict__ bout,
                                                     float* __restrict__ out) {
    // 57344 B static LDS: per-wave q[32][72], k[32][72], vT[64][40]; probs reuses q;
    // after barrier whole array reused as ao[32][520] bf16.
    __shared__ __align__(16) unsigned short lds[28672];

    const int t = threadIdx.x;
    const int w = t >> 6, L = t & 63;
    const int lr = L & 15, g = L >> 4;
    const long long rb = (long long)blockIdx.x * KNB;

    unsigned short* qsm = lds + w * 2304;            // [32][72]
    unsigned short* ksm = lds + 9216 + w * 2304;     // [32][72]
    unsigned short* vtm = lds + 18432 + w * 2560;    // [64][40]  (vT: [o][j])
    unsigned short* psm = qsm;                       // probs [32][40] (q dead after dots)
    const unsigned short* wfb = (const unsigned short*)(ws + WS_WF);
    const unsigned short* WT  = (const unsigned short*)(ws + WS_WT);

    f32x4 av[2][2][4];                               // [head-slot][i-tile][o-tile]

    #pragma unroll
    for (int hs = 0; hs < 2; ++hs) {
        const int h = w + hs * 4;

        // ---- raw-x A-fragments (BN folded into weights): row = lr(+16), k = g*8..+7
        bf16x8 xa[2];
        #pragma unroll
        for (int it = 0; it < 2; ++it) {
            const float* xp = x + (rb + it * 16 + lr) * DIM + h * DPG + g * 8;
            xa[it] = pack8(*(const f32x4*)xp, *(const f32x4*)(xp + 4));
        }

        // ---- QKV via MFMA, bias in accumulator init; stage q,k as [row][d], v as vT[o][j]
        #pragma unroll
        for (int m = 0; m < 3; ++m) {
            #pragma unroll
            for (int ot = 0; ot < 4; ++ot) {
                const int o = ot * 16 + lr;
                bf16x8 wf = *(const bf16x8*)(wfb + ((m * HEADS + h) * DH + o) * DPG + g * 8);
                float bv = ws[WS_QB + (m * HEADS + h) * DH + o];
                #pragma unroll
                for (int it = 0; it < 2; ++it) {
                    f32x4 c = {bv, bv, bv, bv};
                    c = __builtin_amdgcn_mfma_f32_16x16x32_bf16(xa[it], wf, c, 0, 0, 0);
                    if (m == 0) {
                        #pragma unroll
                        for (int r = 0; r < 4; ++r)
                            qsm[(it * 16 + g * 4 + r) * 72 + o] = f2bf(c[r]);
                    } else if (m == 1) {
                        #pragma unroll
                        for (int r = 0; r < 4; ++r)
                            ksm[(it * 16 + g * 4 + r) * 72 + o] = f2bf(c[r]);
                    } else {
                        uint2 u;                      // vT[o][j..j+3], 8B aligned
                        u.x = packbf(c[0], c[1]);
                        u.y = packbf(c[2], c[3]);
                        *(uint2*)(vtm + o * 40 + it * 16 + g * 4) = u;
                    }
                }
            }
        }

        // ---- dots = q @ k^T  (D: col = j, row = i)
        f32x4 dt[2][2];
        #pragma unroll
        for (int it = 0; it < 2; ++it)
            #pragma unroll
            for (int jt = 0; jt < 2; ++jt) dt[it][jt] = (f32x4){0.f, 0.f, 0.f, 0.f};
        #pragma unroll
        for (int ksp = 0; ksp < 2; ++ksp) {
            bf16x8 qa[2], kb[2];
            #pragma unroll
            for (int it = 0; it < 2; ++it)
                qa[it] = *(const bf16x8*)(qsm + (it * 16 + lr) * 72 + ksp * 32 + g * 8);
            #pragma unroll
            for (int jt = 0; jt < 2; ++jt)
                kb[jt] = *(const bf16x8*)(ksm + (jt * 16 + lr) * 72 + ksp * 32 + g * 8);
            #pragma unroll
            for (int it = 0; it < 2; ++it)
                #pragma unroll
                for (int jt = 0; jt < 2; ++jt)
                    dt[it][jt] = __builtin_amdgcn_mfma_f32_16x16x32_bf16(qa[it], kb[jt], dt[it][jt], 0, 0, 0);
        }

        // ---- softmax over j (cols): local pair + xor-reduce over the 16-lane col group
        #pragma unroll
        for (int it = 0; it < 2; ++it)
            #pragma unroll
            for (int r = 0; r < 4; ++r) {
                float m0 = fmaxf(dt[it][0][r], dt[it][1][r]);
                m0 = fmaxf(m0, __shfl_xor(m0, 1, 64));
                m0 = fmaxf(m0, __shfl_xor(m0, 2, 64));
                m0 = fmaxf(m0, __shfl_xor(m0, 4, 64));
                m0 = fmaxf(m0, __shfl_xor(m0, 8, 64));
                float e0 = __expf(dt[it][0][r] - m0);
                float e1 = __expf(dt[it][1][r] - m0);
                float s = e0 + e1;
                s += __shfl_xor(s, 1, 64);
                s += __shfl_xor(s, 2, 64);
                s += __shfl_xor(s, 4, 64);
                s += __shfl_xor(s, 8, 64);
                float inv = 1.f / s;
                int row = (it * 16 + g * 4 + r) * 40;
                psm[row + lr]      = f2bf(e0 * inv);
                psm[row + 16 + lr] = f2bf(e1 * inv);
            }

        // ---- AV: A = probs[i][j], B = vT[o][j]
        #pragma unroll
        for (int it = 0; it < 2; ++it) {
            bf16x8 pa = *(const bf16x8*)(psm + (it * 16 + lr) * 40 + g * 8);
            #pragma unroll
            for (int ot = 0; ot < 4; ++ot) {
                bf16x8 vb = *(const bf16x8*)(vtm + (ot * 16 + lr) * 40 + g * 8);
                f32x4 c = {0.f, 0.f, 0.f, 0.f};
                av[hs][it][ot] = __builtin_amdgcn_mfma_f32_16x16x32_bf16(pa, vb, c, 0, 0, 0);
            }
        }
    }

    // ---- gather full-point ao[32][512] in LDS (av held in regs across barrier)
    __syncthreads();
    unsigned short* aos = lds;                        // [32][520]
    #pragma unroll
    for (int hs = 0; hs < 2; ++hs)
        #pragma unroll
        for (int it = 0; it < 2; ++it)
            #pragma unroll
            for (int ot = 0; ot < 4; ++ot)
                #pragma unroll
                for (int r = 0; r < 4; ++r)
                    aos[(it * 16 + g * 4 + r) * 520 + (w + hs * 4) * 64 + ot * 16 + lr]
                        = f2bf(av[hs][it][ot][r]);
    __syncthreads();

    // ---- output GEMM: out[32x256] = ao[32x512] @ WoutT^T + bout. Wave w: cols w*64..+63.
    f32x4 oacc[2][4];
    #pragma unroll
    for (int n4 = 0; n4 < 4; ++n4) {
        float bv = bout[(w * 4 + n4) * 16 + lr];
        oacc[0][n4] = (f32x4){bv, bv, bv, bv};
        oacc[1][n4] = (f32x4){bv, bv, bv, bv};
    }
    #pragma unroll 4
    for (int ksp = 0; ksp < 16; ++ksp) {
        bf16x8 a0 = *(const bf16x8*)(aos + lr * 520 + ksp * 32 + g * 8);
        bf16x8 a1 = *(const bf16x8*)(aos + (16 + lr) * 520 + ksp * 32 + g * 8);
        #pragma unroll
        for (int n4 = 0; n4 < 4; ++n4) {
            const int n = (w * 4 + n4) * 16 + lr;
            bf16x8 bvv = *(const bf16x8*)(WT + (size_t)n * INNER + ksp * 32 + g * 8);
            oacc[0][n4] = __builtin_amdgcn_mfma_f32_16x16x32_bf16(a0, bvv, oacc[0][n4], 0, 0, 0);
            oacc[1][n4] = __builtin_amdgcn_mfma_f32_16x16x32_bf16(a1, bvv, oacc[1][n4], 0, 0, 0);
        }
    }
    #pragma unroll
    for (int it = 0; it < 2; ++it)
        #pragma unroll
        for (int n4 = 0; n4 < 4; ++n4)
            #pragma unroll
            for (int r = 0; r < 4; ++r)
                out[(rb + it * 16 + g * 4 + r) * DIM + (w * 4 + n4) * 16 + lr] = oacc[it][n4][r];
}

extern "C" void kernel_launch(void* const* d_in, const int* in_sizes, int n_in,
                              void* d_out, int out_size, void* d_ws, size_t ws_size,
                              hipStream_t stream) {
    const float* x  = (const float*)d_in[0];
    const float* g  = (const float*)d_in[1];
    const float* b  = (const float*)d_in[2];
    const float* wq = (const float*)d_in[3];
    const float* wk = (const float*)d_in[4];
    const float* wv = (const float*)d_in[5];
    const float* wo = (const float*)d_in[6];
    const float* bo = (const float*)d_in[7];
    float* ws = (float*)d_ws;

    int rows = in_sizes[0] / DIM;       // 131072
    int npts = rows / KNB;              // 4096

    hipMemsetAsync(d_ws, 0, 2048, stream);
    bn_stats_k<<<1024, 256, 0, stream>>>((const f32x4*)x, ws, rows * (DIM / 4));
    bn_finalize_k<<<1, 256, 0, stream>>>(g, b, ws, 1.0f / (float)rows);
    wt_k<<<INNER, 256, 0, stream>>>(wo, ws);
    fold_k<<<dim3(3, HEADS), DH, 0, stream>>>(wq, wk, wv, ws);
    attn_fused<<<npts, 256, 0, stream>>>(x, ws, bo, (float*)d_out);
}

// Round 3
// 428.387 us; speedup vs baseline: 2.7415x; 1.2380x over previous
//
#include <hip/hip_runtime.h>

#define DIM    256
#define HEADS  8
#define DH     64
#define DPG    32
#define KNB    32
#define INNER  512
#define EPS    1e-5f

// ws float offsets
#define WS_SUM  0
#define WS_SSQ  256
#define WS_SC   512
#define WS_SH   768
#define WS_WF   1024      // bf16 [3][8][64][32] folded weights  -> 24576 floats
#define WS_QB   25600     // f32  [3][8][64] folded biases       -> 1536 floats
#define WS_WT   27136     // bf16 [256][512] WoutT               -> 65536 floats (end 92672 floats = 371KB)

typedef float f32x4  __attribute__((ext_vector_type(4)));
typedef short bf16x8 __attribute__((ext_vector_type(8)));

__device__ __forceinline__ unsigned short f2bf(float f){
    unsigned u = __float_as_uint(f);
    u += 0x7fffu + ((u >> 16) & 1u);          // RNE
    return (unsigned short)(u >> 16);
}
__device__ __forceinline__ unsigned packbf(float a, float b){
    return (unsigned)f2bf(a) | ((unsigned)f2bf(b) << 16);
}
__device__ __forceinline__ bf16x8 pack8(f32x4 a, f32x4 b){
    union { unsigned u[4]; bf16x8 v; } r;
    r.u[0] = packbf(a[0], a[1]); r.u[1] = packbf(a[2], a[3]);
    r.u[2] = packbf(b[0], b[1]); r.u[3] = packbf(b[2], b[3]);
    return r.v;
}

// XOR-swizzled LDS index maps (shorts). q/k: 32 rows x 64 cols, stride 64.
// vT: 64 rows x 32 cols, stride 32. Swizzle keeps 8-short (16B) granules.
#define QKSWZ(row, col) ((row) * 64 + ((col) ^ ((((row) ^ ((row) >> 3)) & 7) << 3)))
#define VTSWZ(row, col) ((row) * 32 + ((col) ^ (((row) & 3) << 3)))

// ---------------- BN statistics (vectorized float4, spread atomics) ----------------
__global__ __launch_bounds__(256) void bn_stats_k(const f32x4* __restrict__ x4,
                                                  float* __restrict__ ws, int n4) {
    __shared__ f32x4 rs[4][64], rss[4][64];
    int tid = blockIdx.x * 256 + threadIdx.x;
    int stride = gridDim.x * 256;
    f32x4 s  = {0.f, 0.f, 0.f, 0.f};
    f32x4 ss = {0.f, 0.f, 0.f, 0.f};
    for (int f = tid; f < n4; f += stride) {     // stride % 64 == 0 -> c4 invariant
        f32x4 v = x4[f];
        s += v; ss += v * v;
    }
    int c4 = threadIdx.x & 63, wv = threadIdx.x >> 6;
    rs[wv][c4] = s; rss[wv][c4] = ss;
    __syncthreads();
    // thread t owns channel t; flat float view: rs[w][c4][comp] at w*256 + ch
    const float* rsf  = (const float*)rs;
    const float* rssf = (const float*)rss;
    int ch = threadIdx.x;
    float S = rsf[ch]  + rsf[256 + ch]  + rsf[512 + ch]  + rsf[768 + ch];
    float Q = rssf[ch] + rssf[256 + ch] + rssf[512 + ch] + rssf[768 + ch];
    atomicAdd(&ws[WS_SUM + ch], S);
    atomicAdd(&ws[WS_SSQ + ch], Q);
}

__global__ __launch_bounds__(256) void bn_finalize_k(const float* __restrict__ g,
                                                     const float* __restrict__ b,
                                                     float* __restrict__ ws, float inv_n) {
    int c = threadIdx.x;
    float mean = ws[WS_SUM + c] * inv_n;
    float var  = ws[WS_SSQ + c] * inv_n - mean * mean;
    float sc   = g[c] * rsqrtf(var + EPS);
    ws[WS_SC + c] = sc;
    ws[WS_SH + c] = b[c] - mean * sc;
}

// ---------------- Wout transpose to bf16 (64x64 LDS tile, coalesced uint4 writes) ----
__global__ __launch_bounds__(256) void wt_k(const float* __restrict__ Wout, float* __restrict__ ws) {
    __shared__ unsigned short tile[64][65];
    const int k0 = blockIdx.x * 64, n0 = blockIdx.y * 64;
    const int t = threadIdx.x;
    #pragma unroll
    for (int i = 0; i < 16; ++i) {
        int e = t + 256 * i;
        int kk = e >> 6, nn = e & 63;
        tile[kk][nn] = f2bf(Wout[(k0 + kk) * DIM + n0 + nn]);
    }
    __syncthreads();
    unsigned short* wt = (unsigned short*)(ws + WS_WT);
    #pragma unroll
    for (int i = 0; i < 2; ++i) {
        int f = t + 256 * i;               // 0..511
        int nn = f >> 3, kc = f & 7;
        union { unsigned short s[8]; uint4 u; } pk;
        #pragma unroll
        for (int j = 0; j < 8; ++j) pk.s[j] = tile[kc * 8 + j][nn];
        *(uint4*)(wt + (size_t)(n0 + nn) * INNER + k0 + kc * 8) = pk.u;
    }
}

// ---------------- fold BN into QKV weights/biases (coalesced, LDS-staged) -----------
__global__ __launch_bounds__(256) void fold_k(const float* __restrict__ Wq,
                                              const float* __restrict__ Wk,
                                              const float* __restrict__ Wv,
                                              float* __restrict__ ws) {
    __shared__ float wl[64][33];
    __shared__ float scs[DPG], shs[DPG];
    const int m = blockIdx.x, h = blockIdx.y, t = threadIdx.x;
    const float* W = (m == 0 ? Wq : (m == 1 ? Wk : Wv)) + h * DH * DPG;
    if (t < DPG) { scs[t] = ws[WS_SC + h * DPG + t]; shs[t] = ws[WS_SH + h * DPG + t]; }
    #pragma unroll
    for (int i = 0; i < 8; ++i) {
        int e = t + 256 * i;               // 0..2047 coalesced
        wl[e >> 5][e & 31] = W[e];
    }
    __syncthreads();
    const float qsc = (m == 0) ? 0.125f : 1.f;   // dim_head^-0.5 folded into q
    unsigned short* wf = (unsigned short*)(ws + WS_WF) + (m * HEADS + h) * DH * DPG;
    {
        int o = t >> 2, c0 = (t & 3) * 8;
        union { unsigned short s[8]; uint4 u; } pk;
        #pragma unroll
        for (int j = 0; j < 8; ++j) pk.s[j] = f2bf(wl[o][c0 + j] * scs[c0 + j] * qsc);
        *(uint4*)(wf + o * DPG + c0) = pk.u;
    }
    if (t < DH) {
        float bias = 0.f;
        #pragma unroll
        for (int c = 0; c < DPG; ++c) bias += shs[c] * wl[t][c];
        ws[WS_QB + (m * HEADS + h) * DH + t] = bias * qsc;
    }
}

// ---------------- fused BN + QKV + attention + output GEMM (all MFMA) ----------------
// grid = npts (4096), block = 256 (4 waves). Wave w handles heads {w, w+4} of its point.
// MFMA 16x16x32 fragment convention (verified): A/B frag: lane&15 = row, lane>>4 = k-octet,
// 8 contiguous k per lane. D: col = lane&15, row = (lane>>4)*4 + reg.
__global__ __launch_bounds__(256, 3) void attn_fused(const float* __restrict__ x,
                                                     const float* __restrict__ ws,
                                                     const float* __restrict__ bout,
                                                     float* __restrict__ out) {
    // 49152 B static LDS: per-wave swizzled q[32][64], k[32][64], vT[64][32];
    // probs reuses q; after barrier whole array reused as ao[32][520] bf16.
    __shared__ __align__(16) unsigned short lds[24576];

    const int t = threadIdx.x;
    const int w = t >> 6, L = t & 63;
    const int lr = L & 15, g = L >> 4;
    const long long rb = (long long)blockIdx.x * KNB;

    unsigned short* qsm = lds + w * 2048;            // [32][64] swizzled
    unsigned short* ksm = lds + 8192 + w * 2048;     // [32][64] swizzled
    unsigned short* vtm = lds + 16384 + w * 2048;    // [64][32] swizzled (vT: [o][j])
    unsigned short* psm = qsm;                       // probs [32][<=32] (q dead after dots)
    const unsigned short* wfb = (const unsigned short*)(ws + WS_WF);
    const unsigned short* WT  = (const unsigned short*)(ws + WS_WT);

    f32x4 av[2][2][4];                               // [head-slot][i-tile][o-tile]

    #pragma unroll
    for (int hs = 0; hs < 2; ++hs) {
        const int h = w + hs * 4;

        // ---- raw-x A-fragments (BN folded into weights): row = lr(+16), k = g*8..+7
        bf16x8 xa[2];
        #pragma unroll
        for (int it = 0; it < 2; ++it) {
            const float* xp = x + (rb + it * 16 + lr) * DIM + h * DPG + g * 8;
            xa[it] = pack8(*(const f32x4*)xp, *(const f32x4*)(xp + 4));
        }

        // ---- QKV via MFMA, bias in accumulator init; stage q,k as [row][d], v as vT[o][j]
        #pragma unroll
        for (int m = 0; m < 3; ++m) {
            #pragma unroll
            for (int ot = 0; ot < 4; ++ot) {
                const int o = ot * 16 + lr;
                bf16x8 wf = *(const bf16x8*)(wfb + ((m * HEADS + h) * DH + o) * DPG + g * 8);
                float bv = ws[WS_QB + (m * HEADS + h) * DH + o];
                #pragma unroll
                for (int it = 0; it < 2; ++it) {
                    f32x4 c = {bv, bv, bv, bv};
                    c = __builtin_amdgcn_mfma_f32_16x16x32_bf16(xa[it], wf, c, 0, 0, 0);
                    if (m == 0) {
                        #pragma unroll
                        for (int r = 0; r < 4; ++r) {
                            int row = it * 16 + g * 4 + r;
                            qsm[QKSWZ(row, o)] = f2bf(c[r]);
                        }
                    } else if (m == 1) {
                        #pragma unroll
                        for (int r = 0; r < 4; ++r) {
                            int row = it * 16 + g * 4 + r;
                            ksm[QKSWZ(row, o)] = f2bf(c[r]);
                        }
                    } else {
                        uint2 u;                      // vT[o][j..j+3], 8B aligned
                        u.x = packbf(c[0], c[1]);
                        u.y = packbf(c[2], c[3]);
                        *(uint2*)(vtm + VTSWZ(o, it * 16 + g * 4)) = u;
                    }
                }
            }
        }

        // ---- dots = q @ k^T  (D: col = j, row = i)
        f32x4 dt[2][2];
        #pragma unroll
        for (int it = 0; it < 2; ++it)
            #pragma unroll
            for (int jt = 0; jt < 2; ++jt) dt[it][jt] = (f32x4){0.f, 0.f, 0.f, 0.f};
        #pragma unroll
        for (int ksp = 0; ksp < 2; ++ksp) {
            bf16x8 qa[2], kb[2];
            #pragma unroll
            for (int it = 0; it < 2; ++it)
                qa[it] = *(const bf16x8*)(qsm + QKSWZ(it * 16 + lr, ksp * 32 + g * 8));
            #pragma unroll
            for (int jt = 0; jt < 2; ++jt)
                kb[jt] = *(const bf16x8*)(ksm + QKSWZ(jt * 16 + lr, ksp * 32 + g * 8));
            #pragma unroll
            for (int it = 0; it < 2; ++it)
                #pragma unroll
                for (int jt = 0; jt < 2; ++jt)
                    dt[it][jt] = __builtin_amdgcn_mfma_f32_16x16x32_bf16(qa[it], kb[jt], dt[it][jt], 0, 0, 0);
        }

        // ---- softmax over j (cols): local pair + xor-reduce over the 16-lane col group
        #pragma unroll
        for (int it = 0; it < 2; ++it)
            #pragma unroll
            for (int r = 0; r < 4; ++r) {
                float m0 = fmaxf(dt[it][0][r], dt[it][1][r]);
                m0 = fmaxf(m0, __shfl_xor(m0, 1, 64));
                m0 = fmaxf(m0, __shfl_xor(m0, 2, 64));
                m0 = fmaxf(m0, __shfl_xor(m0, 4, 64));
                m0 = fmaxf(m0, __shfl_xor(m0, 8, 64));
                float e0 = __expf(dt[it][0][r] - m0);
                float e1 = __expf(dt[it][1][r] - m0);
                float s = e0 + e1;
                s += __shfl_xor(s, 1, 64);
                s += __shfl_xor(s, 2, 64);
                s += __shfl_xor(s, 4, 64);
                s += __shfl_xor(s, 8, 64);
                float inv = 1.f / s;
                int row = it * 16 + g * 4 + r;
                psm[QKSWZ(row, lr)]      = f2bf(e0 * inv);
                psm[QKSWZ(row, lr + 16)] = f2bf(e1 * inv);
            }

        // ---- AV: A = probs[i][j], B = vT[o][j]
        #pragma unroll
        for (int it = 0; it < 2; ++it) {
            bf16x8 pa = *(const bf16x8*)(psm + QKSWZ(it * 16 + lr, g * 8));
            #pragma unroll
            for (int ot = 0; ot < 4; ++ot) {
                bf16x8 vb = *(const bf16x8*)(vtm + VTSWZ(ot * 16 + lr, g * 8));
                f32x4 c = {0.f, 0.f, 0.f, 0.f};
                av[hs][it][ot] = __builtin_amdgcn_mfma_f32_16x16x32_bf16(pa, vb, c, 0, 0, 0);
            }
        }
    }

    // ---- gather full-point ao[32][512] in LDS (av held in regs across barrier)
    __syncthreads();
    unsigned short* aos = lds;                        // [32][520]
    #pragma unroll
    for (int hs = 0; hs < 2; ++hs)
        #pragma unroll
        for (int it = 0; it < 2; ++it)
            #pragma unroll
            for (int ot = 0; ot < 4; ++ot)
                #pragma unroll
                for (int r = 0; r < 4; ++r)
                    aos[(it * 16 + g * 4 + r) * 520 + (w + hs * 4) * 64 + ot * 16 + lr]
                        = f2bf(av[hs][it][ot][r]);
    __syncthreads();

    // ---- output GEMM: out[32x256] = ao[32x512] @ WoutT^T + bout. Wave w: cols w*64..+63.
    f32x4 oacc[2][4];
    #pragma unroll
    for (int n4 = 0; n4 < 4; ++n4) {
        float bv = bout[(w * 4 + n4) * 16 + lr];
        oacc[0][n4] = (f32x4){bv, bv, bv, bv};
        oacc[1][n4] = (f32x4){bv, bv, bv, bv};
    }
    #pragma unroll 4
    for (int ksp = 0; ksp < 16; ++ksp) {
        bf16x8 a0 = *(const bf16x8*)(aos + lr * 520 + ksp * 32 + g * 8);
        bf16x8 a1 = *(const bf16x8*)(aos + (16 + lr) * 520 + ksp * 32 + g * 8);
        #pragma unroll
        for (int n4 = 0; n4 < 4; ++n4) {
            const int n = (w * 4 + n4) * 16 + lr;
            bf16x8 bvv = *(const bf16x8*)(WT + (size_t)n * INNER + ksp * 32 + g * 8);
            oacc[0][n4] = __builtin_amdgcn_mfma_f32_16x16x32_bf16(a0, bvv, oacc[0][n4], 0, 0, 0);
            oacc[1][n4] = __builtin_amdgcn_mfma_f32_16x16x32_bf16(a1, bvv, oacc[1][n4], 0, 0, 0);
        }
    }
    #pragma unroll
    for (int it = 0; it < 2; ++it)
        #pragma unroll
        for (int n4 = 0; n4 < 4; ++n4)
            #pragma unroll
            for (int r = 0; r < 4; ++r)
                out[(rb + it * 16 + g * 4 + r) * DIM + (w * 4 + n4) * 16 + lr] = oacc[it][n4][r];
}

extern "C" void kernel_launch(void* const* d_in, const int* in_sizes, int n_in,
                              void* d_out, int out_size, void* d_ws, size_t ws_size,
                              hipStream_t stream) {
    const float* x  = (const float*)d_in[0];
    const float* g  = (const float*)d_in[1];
    const float* b  = (const float*)d_in[2];
    const float* wq = (const float*)d_in[3];
    const float* wk = (const float*)d_in[4];
    const float* wv = (const float*)d_in[5];
    const float* wo = (const float*)d_in[6];
    const float* bo = (const float*)d_in[7];
    float* ws = (float*)d_ws;

    int rows = in_sizes[0] / DIM;       // 131072
    int npts = rows / KNB;              // 4096

    hipMemsetAsync(d_ws, 0, 2048, stream);
    bn_stats_k<<<512, 256, 0, stream>>>((const f32x4*)x, ws, rows * (DIM / 4));
    bn_finalize_k<<<1, 256, 0, stream>>>(g, b, ws, 1.0f / (float)rows);
    wt_k<<<dim3(INNER / 64, DIM / 64), 256, 0, stream>>>(wo, ws);
    fold_k<<<dim3(3, HEADS), 256, 0, stream>>>(wq, wk, wv, ws);
    attn_fused<<<npts, 256, 0, stream>>>(x, ws, bo, (float*)d_out);
}